// Round 1
// baseline (340.327 us; speedup 1.0000x reference)
//
#include <hip/hip_runtime.h>

#define NROWS 131072
#define DDIM  64
#define KCB   1024

#define BR  64   // rows per block
#define BK  64   // codebook cols per chunk
#define PAD 68   // padded LDS row stride in floats (keeps 16B alignment)

__global__ __launch_bounds__(256)
void codebook_l2_kernel(const float* __restrict__ x,
                        const float* __restrict__ cb,
                        float* __restrict__ out_codevec,
                        float* __restrict__ out_codes,
                        float* __restrict__ out_l2) {
    __shared__ float xs[BR * PAD];
    __shared__ float cs[BK * PAD];
    __shared__ float xsq_s[BR];
    __shared__ float csq_s[BK];
    __shared__ int   best_s[BR];

    const int tid  = threadIdx.x;
    const int tx   = tid & 15;   // col-lane (16)
    const int ty   = tid >> 4;   // row-group (16)
    const int row0 = blockIdx.x * BR;

    // ---- stage x tile (64x64) + per-row ||x||^2 ----
    {
        const int r  = tid >> 2;          // row 0..63
        const int c0 = (tid & 3) * 16;    // 16 floats per thread
        const float4* src = (const float4*)(x + (size_t)(row0 + r) * DDIM + c0);
        float s = 0.f;
#pragma unroll
        for (int j = 0; j < 4; ++j) {
            float4 v = src[j];
            *(float4*)&xs[r * PAD + c0 + j * 4] = v;
            s += v.x * v.x + v.y * v.y + v.z * v.z + v.w * v.w;
        }
        s += __shfl_xor(s, 1);
        s += __shfl_xor(s, 2);
        if ((tid & 3) == 0) xsq_s[r] = s;
    }
    __syncthreads();

    float xsq[4];
#pragma unroll
    for (int i = 0; i < 4; ++i) xsq[i] = xsq_s[ty * 4 + i];

    float minval[4];
    int   minidx[4];
#pragma unroll
    for (int i = 0; i < 4; ++i) { minval[i] = 3.4e38f; minidx[i] = 0; }

    for (int k0 = 0; k0 < KCB; k0 += BK) {
        // ---- stage codebook chunk (64x64) + per-col ||c||^2 ----
        {
            const int r  = tid >> 2;
            const int c0 = (tid & 3) * 16;
            const float4* src = (const float4*)(cb + (size_t)(k0 + r) * DDIM + c0);
            float s = 0.f;
#pragma unroll
            for (int j = 0; j < 4; ++j) {
                float4 v = src[j];
                *(float4*)&cs[r * PAD + c0 + j * 4] = v;
                s += v.x * v.x + v.y * v.y + v.z * v.z + v.w * v.w;
            }
            s += __shfl_xor(s, 1);
            s += __shfl_xor(s, 2);
            if ((tid & 3) == 0) csq_s[r] = s;
        }
        __syncthreads();

        float acc[4][4];
#pragma unroll
        for (int i = 0; i < 4; ++i)
#pragma unroll
            for (int j = 0; j < 4; ++j) acc[i][j] = 0.f;

#pragma unroll
        for (int dd = 0; dd < DDIM; dd += 4) {
            float4 a[4], b[4];
#pragma unroll
            for (int i = 0; i < 4; ++i)
                a[i] = *(const float4*)&xs[(ty * 4 + i) * PAD + dd];
#pragma unroll
            for (int j = 0; j < 4; ++j)
                b[j] = *(const float4*)&cs[(tx + 16 * j) * PAD + dd];
#pragma unroll
            for (int i = 0; i < 4; ++i)
#pragma unroll
                for (int j = 0; j < 4; ++j) {
                    acc[i][j] += a[i].x * b[j].x;
                    acc[i][j] += a[i].y * b[j].y;
                    acc[i][j] += a[i].z * b[j].z;
                    acc[i][j] += a[i].w * b[j].w;
                }
        }

        float cq[4];
#pragma unroll
        for (int j = 0; j < 4; ++j) cq[j] = csq_s[tx + 16 * j];

#pragma unroll
        for (int i = 0; i < 4; ++i) {
            float* dst = out_l2 + (size_t)(row0 + ty * 4 + i) * KCB + k0;
#pragma unroll
            for (int j = 0; j < 4; ++j) {
                float l2 = xsq[i] + cq[j] - 2.f * acc[i][j];
                dst[tx + 16 * j] = l2;
                int kk = k0 + tx + 16 * j;
                if (l2 < minval[i]) { minval[i] = l2; minidx[i] = kk; }
            }
        }
        __syncthreads();  // protect cs/csq_s before next chunk
    }

    // ---- argmin reduce across the 16 col-lanes (same wave) ----
#pragma unroll
    for (int i = 0; i < 4; ++i) {
#pragma unroll
        for (int m = 1; m < 16; m <<= 1) {
            float ov = __shfl_xor(minval[i], m);
            int   oi = __shfl_xor(minidx[i], m);
            if (ov < minval[i] || (ov == minval[i] && oi < minidx[i])) {
                minval[i] = ov; minidx[i] = oi;
            }
        }
        if (tx == 0) best_s[ty * 4 + i] = minidx[i];
    }
    __syncthreads();

    // ---- codes (as float) ----
    if (tid < BR) out_codes[row0 + tid] = (float)best_s[tid];

    // ---- code_vec gather (codebook is L2-hot) ----
    {
        const int r  = tid >> 2;
        const int c0 = (tid & 3) * 16;
        const int b  = best_s[r];
        const float4* src = (const float4*)(cb + (size_t)b * DDIM + c0);
        float4* dst = (float4*)(out_codevec + (size_t)(row0 + r) * DDIM + c0);
#pragma unroll
        for (int j = 0; j < 4; ++j) dst[j] = src[j];
    }
}

extern "C" void kernel_launch(void* const* d_in, const int* in_sizes, int n_in,
                              void* d_out, int out_size, void* d_ws, size_t ws_size,
                              hipStream_t stream) {
    (void)in_sizes; (void)n_in; (void)d_ws; (void)ws_size; (void)out_size;
    const float* x  = (const float*)d_in[0];
    const float* cb = (const float*)d_in[1];

    float* out_codevec = (float*)d_out;                              // N*D
    float* out_codes   = out_codevec + (size_t)NROWS * DDIM;         // N
    float* out_l2      = out_codes + NROWS;                          // N*K

    dim3 grid(NROWS / BR);
    dim3 block(256);
    codebook_l2_kernel<<<grid, block, 0, stream>>>(x, cb, out_codevec, out_codes, out_l2);
}